// Round 1
// baseline (661.784 us; speedup 1.0000x reference)
//
#include <hip/hip_runtime.h>
#include <math.h>

#define NROWS 16384   // B*T
#define DIM   128
#define NCODE 8192
#define EPSF  1e-12f

// ---------------- ws layout (floats) ----------------
// cb       : [0,            1048576)   8192*128
// cnorm2   : [1048576,      1056768)   8192
// scale    : [1056768,      1056896)   128
// cand_val : [1056896,      1089664)   16384*2  (val per code-half)
// cand_idx : [1089664,      1122432)   16384*2  (int)
// partials : [1122432,      1126528)   4096
// total 4,506,112 bytes

__device__ __forceinline__ float wave_sum(float x) {
#pragma unroll
  for (int off = 32; off > 0; off >>= 1) x += __shfl_xor(x, off, 64);
  return x;
}

// --- K0a: scale[d] = g[d] / ||v[d]|| -------------------------------------
__global__ void scale_kernel(const float* __restrict__ v,
                             const float* __restrict__ g,
                             float* __restrict__ scale) {
  const int d = threadIdx.x;  // 128 threads
  float ss = 0.f;
  for (int k = 0; k < DIM; ++k) {
    const float x = v[d * DIM + k];
    ss = fmaf(x, x, ss);
  }
  scale[d] = g[d] / sqrtf(ss);
}

// --- K0b: cb[c][d] = dot(fc[c], v[d]) * scale[d] + bias[d]; cnorm2[c] ----
__global__ __launch_bounds__(256) void codebook_kernel(
    const float* __restrict__ fc, const float* __restrict__ v,
    const float* __restrict__ scale, const float* __restrict__ bias,
    float* __restrict__ cb, float* __restrict__ cnorm2) {
  const int c = blockIdx.x * 4 + (threadIdx.x >> 6);
  const int lane = threadIdx.x & 63;
  float a0 = 0.f, a1 = 0.f;
  for (int k = 0; k < DIM; ++k) {
    const float f = fc[c * DIM + k];
    a0 = fmaf(f, v[lane * DIM + k], a0);
    a1 = fmaf(f, v[(lane + 64) * DIM + k], a1);
  }
  const float o0 = fmaf(a0, scale[lane], bias[lane]);
  const float o1 = fmaf(a1, scale[lane + 64], bias[lane + 64]);
  cb[c * DIM + lane] = o0;
  cb[c * DIM + lane + 64] = o1;
  const float ss = wave_sum(fmaf(o0, o0, o1 * o1));
  if (lane == 0) cnorm2[c] = ss;
}

// --- K1: fused distance GEMM + argmin ------------------------------------
// grid 256 = 128 row-blocks x 2 code-halves; block 256 threads.
// Per thread: 8 rows x 8 codes (strided by 16), k vectorized by float4.
__global__ __launch_bounds__(256, 1) void argmin_kernel(
    const float* __restrict__ z, const float* __restrict__ cb,
    const float* __restrict__ cnorm2, float* __restrict__ cand_val,
    int* __restrict__ cand_idx) {
  __shared__ float zs[128][DIM];   // 64 KiB, reads are 4-address broadcasts
  __shared__ float cs[128][DIM];   // 64 KiB, XOR-swizzled 16B slots

  const int tid = threadIdx.x;
  const int rb = blockIdx.x >> 1;        // row block
  const int ch = blockIdx.x & 1;         // code half
  const int row0 = rb * 128;
  const int code0 = ch * (NCODE / 2);

  // stage z tile (linear)
  for (int i = tid; i < 128 * 32; i += 256) {
    const int r = i >> 5, f = i & 31;
    *(float4*)&zs[r][f << 2] = *(const float4*)&z[(row0 + r) * DIM + (f << 2)];
  }

  const int tx = tid & 15, ty = tid >> 4;
  const int sw = tx & 7;  // read-side swizzle constant (row = tx + 16j, (row&7)==tx&7)

  float best[8];
  int besti[8];
#pragma unroll
  for (int r = 0; r < 8; ++r) { best[r] = 3.4e38f; besti[r] = 0; }

  for (int cc = 0; cc < NCODE / 2; cc += 128) {
    __syncthreads();  // protect cs from previous iteration's readers
    // stage cb chunk: LDS slot [r][f] holds global 16B-slot (f ^ (r&7))
    for (int i = tid; i < 128 * 32; i += 256) {
      const int r = i >> 5, f = i & 31;
      const int fg = f ^ (r & 7);
      *(float4*)&cs[r][f << 2] =
          *(const float4*)&cb[(code0 + cc + r) * DIM + (fg << 2)];
    }
    __syncthreads();

    float acc[8][8];
#pragma unroll
    for (int r = 0; r < 8; ++r)
#pragma unroll
      for (int j = 0; j < 8; ++j) acc[r][j] = 0.f;

    for (int k = 0; k < DIM; k += 4) {
      const int f = k >> 2;
      float4 zr[8], cr[8];
#pragma unroll
      for (int r = 0; r < 8; ++r) zr[r] = *(const float4*)&zs[ty + 16 * r][k];
      const int col = ((f ^ sw) << 2);
#pragma unroll
      for (int j = 0; j < 8; ++j) cr[j] = *(const float4*)&cs[tx + 16 * j][col];
#pragma unroll
      for (int r = 0; r < 8; ++r)
#pragma unroll
        for (int j = 0; j < 8; ++j) {
          acc[r][j] = fmaf(zr[r].x, cr[j].x, acc[r][j]);
          acc[r][j] = fmaf(zr[r].y, cr[j].y, acc[r][j]);
          acc[r][j] = fmaf(zr[r].z, cr[j].z, acc[r][j]);
          acc[r][j] = fmaf(zr[r].w, cr[j].w, acc[r][j]);
        }
    }

#pragma unroll
    for (int j = 0; j < 8; ++j) {
      const int code = code0 + cc + tx + 16 * j;
      const float cn = cnorm2[code];
#pragma unroll
      for (int r = 0; r < 8; ++r) {
        const float s = fmaf(-2.f, acc[r][j], cn);
        if (s < best[r]) { best[r] = s; besti[r] = code; }  // strict <: first-occurrence wins
      }
    }
  }

  // reduce over the 16 tx lanes (lane = (ty&3)*16 + tx within each wave)
#pragma unroll
  for (int off = 1; off < 16; off <<= 1) {
#pragma unroll
    for (int r = 0; r < 8; ++r) {
      const float ov = __shfl_xor(best[r], off, 64);
      const int oi = __shfl_xor(besti[r], off, 64);
      if (ov < best[r] || (ov == best[r] && oi < besti[r])) {
        best[r] = ov;
        besti[r] = oi;
      }
    }
  }
  if (tx == 0) {
#pragma unroll
    for (int r = 0; r < 8; ++r) {
      const int row = row0 + ty + 16 * r;
      cand_val[row * 2 + ch] = best[r];
      cand_idx[row * 2 + ch] = besti[r];
    }
  }
}

// --- K2: merge candidates, gather, rotation trick, commit partials -------
__global__ __launch_bounds__(256) void rotate_kernel(
    const float* __restrict__ z, const float* __restrict__ cb,
    const float* __restrict__ cand_val, const int* __restrict__ cand_idx,
    float* __restrict__ out_zq, float* __restrict__ out_idx,
    float* __restrict__ partials) {
  const int tid = threadIdx.x;
  const int wid = tid >> 6, lane = tid & 63;
  const int row = blockIdx.x * 4 + wid;

  const float v0 = cand_val[row * 2 + 0], v1 = cand_val[row * 2 + 1];
  const int i0 = cand_idx[row * 2 + 0], i1 = cand_idx[row * 2 + 1];
  const int ci = (v1 < v0) ? i1 : i0;  // ties -> lower index (half 0)

  const float z0 = z[row * DIM + lane], z1 = z[row * DIM + lane + 64];
  const float c0 = cb[ci * DIM + lane], c1 = cb[ci * DIM + lane + 64];

  const float ns2 = wave_sum(fmaf(z0, z0, z1 * z1));
  const float nt2 = wave_sum(fmaf(c0, c0, c1 * c1));
  const float ns = sqrtf(ns2), nt = sqrtf(nt2);
  const float dns = fmaxf(ns, EPSF), dnt = fmaxf(nt, EPSF);
  const float u0 = z0 / dns, u1 = z1 / dns;
  const float q0 = c0 / dnt, q1 = c1 / dnt;
  float w0 = u0 + q0, w1 = u1 + q1;
  const float nw = sqrtf(wave_sum(fmaf(w0, w0, w1 * w1)));
  const float dnw = fmaxf(nw, EPSF);
  w0 /= dnw;
  w1 /= dnw;
  const float ew = wave_sum(fmaf(z0, w0, z1 * w1));
  const float eu = wave_sum(fmaf(z0, u0, z1 * u1));
  const float sc = nt / dns;
  const float o0 = (z0 - 2.f * ew * w0 + 2.f * eu * q0) * sc;
  const float o1 = (z1 - 2.f * ew * w1 + 2.f * eu * q1) * sc;
  out_zq[row * DIM + lane] = o0;
  out_zq[row * DIM + lane + 64] = o1;
  if (lane == 0) out_idx[row] = (float)ci;

  const float d0 = z0 - c0, d1 = z1 - c1;
  const float rsum = wave_sum(fmaf(d0, d0, d1 * d1));
  __shared__ float pr[4];
  if (lane == 0) pr[wid] = rsum;
  __syncthreads();
  if (tid == 0) partials[blockIdx.x] = (pr[0] + pr[1]) + (pr[2] + pr[3]);
}

// --- K3: deterministic final reduction for commit ------------------------
__global__ void finalize_kernel(const float* __restrict__ partials,
                                float* __restrict__ out_commit) {
  __shared__ float red[256];
  const int tid = threadIdx.x;
  float s = 0.f;
  for (int i = tid; i < 4096; i += 256) s += partials[i];
  red[tid] = s;
  __syncthreads();
  for (int off = 128; off > 0; off >>= 1) {
    if (tid < off) red[tid] += red[tid + off];
    __syncthreads();
  }
  // commit = COMMIT_W * (mean + 0.25*mean) = 1.25 * sum / (N*D)
  if (tid == 0) out_commit[0] = red[0] * (1.25f / ((float)NROWS * (float)DIM));
}

extern "C" void kernel_launch(void* const* d_in, const int* in_sizes, int n_in,
                              void* d_out, int out_size, void* d_ws,
                              size_t ws_size, hipStream_t stream) {
  const float* z = (const float*)d_in[0];       // (8,2048,128)
  const float* fc = (const float*)d_in[1];      // (8192,128)
  const float* conv_v = (const float*)d_in[2];  // (128,128)
  const float* conv_g = (const float*)d_in[3];  // (128,)
  const float* conv_b = (const float*)d_in[4];  // (128,)
  float* out = (float*)d_out;  // [zq: 2097152][idx: 16384][commit: 1]

  float* ws = (float*)d_ws;
  float* cb = ws;
  float* cnorm2 = ws + 1048576;
  float* scale = ws + 1056768;
  float* cand_val = ws + 1056896;
  int* cand_idx = (int*)(ws + 1089664);
  float* partials = ws + 1122432;

  scale_kernel<<<1, 128, 0, stream>>>(conv_v, conv_g, scale);
  codebook_kernel<<<NCODE / 4, 256, 0, stream>>>(fc, conv_v, scale, conv_b, cb,
                                                 cnorm2);
  argmin_kernel<<<256, 256, 0, stream>>>(z, cb, cnorm2, cand_val, cand_idx);
  rotate_kernel<<<NROWS / 4, 256, 0, stream>>>(z, cb, cand_val, cand_idx, out,
                                               out + 2097152, partials);
  finalize_kernel<<<1, 256, 0, stream>>>(partials, out + 2113536);
}

// Round 2
// 290.813 us; speedup vs baseline: 2.2756x; 2.2756x over previous
//
#include <hip/hip_runtime.h>
#include <math.h>

#define NROWS 16384  // B*T
#define DIM 128
#define NCODE 8192
#define EPSF 1e-12f

typedef float f32x4 __attribute__((ext_vector_type(4)));
typedef __bf16 bf16x8 __attribute__((ext_vector_type(8)));
typedef unsigned short u16x8 __attribute__((ext_vector_type(8)));

// ---------------- MFMA-path ws layout (float offsets) ----------------
// cb       : 0          (1048576)
// cnorm2   : 1048576    (8192)
// scale    : 1056768    (128)
// Zcat     : 1056896    (3145728 floats = 16384*384 ushort)
// CBcat    : 4202624    (1572864 floats =  8192*384 ushort)
// pval     : 5775488    (1048576)  [64 tiles][16384 rows]
// pidx     : 6824064    (1048576)
// fidx     : 7872640    (16384)
// partials : 7889024    (4096)
// end        7893120 floats = 31,572,480 bytes
#define WS_NEED_BYTES 31572480ull

// K = 384 = 12 k-tiles of 32.  Z segs: [hi|hi|lo]; CB segs: [hi|lo|hi].
// Tile layout (both Zcat and CBcat): [blk][kt 0..11][128 rows][32 k] bf16,
// with slot swizzle: elem(r,k) stored at (r<<5) + (k ^ (((r>>1)&3)<<3)).
#define KT 12
#define TILE 4096  // 128*32 elems

__device__ __forceinline__ float wave_sum(float x) {
#pragma unroll
  for (int off = 32; off > 0; off >>= 1) x += __shfl_xor(x, off, 64);
  return x;
}

__device__ __forceinline__ unsigned short f2bf(float x) {
  union { float f; unsigned int u; } v;
  v.f = x;
  unsigned int r = v.u + 0x7fffu + ((v.u >> 16) & 1u);
  return (unsigned short)(r >> 16);
}
__device__ __forceinline__ float bf2f(unsigned short h) {
  union { float f; unsigned int u; } v;
  v.u = ((unsigned int)h) << 16;
  return v.f;
}

__device__ __forceinline__ void gload_lds16(const unsigned short* g,
                                            unsigned short* l) {
  __builtin_amdgcn_global_load_lds(
      (const __attribute__((address_space(1))) void*)g,
      (__attribute__((address_space(3))) void*)l, 16, 0, 0);
}

// --- K0a: scale[d] = g[d] / ||v[d]|| -------------------------------------
__global__ void scale_kernel(const float* __restrict__ v,
                             const float* __restrict__ g,
                             float* __restrict__ scale) {
  const int d = threadIdx.x;  // 128 threads
  float ss = 0.f;
  for (int k = 0; k < DIM; ++k) {
    const float x = v[d * DIM + k];
    ss = fmaf(x, x, ss);
  }
  scale[d] = g[d] / sqrtf(ss);
}

// --- K0b: cb[c][d]; cnorm2[c]; optional CBcat hi/lo swizzled tiles -------
__global__ __launch_bounds__(256) void codebook_kernel(
    const float* __restrict__ fc, const float* __restrict__ v,
    const float* __restrict__ scale, const float* __restrict__ bias,
    float* __restrict__ cb, float* __restrict__ cnorm2,
    unsigned short* __restrict__ cbcat) {
  const int c = blockIdx.x * 4 + (threadIdx.x >> 6);
  const int lane = threadIdx.x & 63;
  float a0 = 0.f, a1 = 0.f;
  for (int k = 0; k < DIM; ++k) {
    const float f = fc[c * DIM + k];
    a0 = fmaf(f, v[lane * DIM + k], a0);
    a1 = fmaf(f, v[(lane + 64) * DIM + k], a1);
  }
  const float o0 = fmaf(a0, scale[lane], bias[lane]);
  const float o1 = fmaf(a1, scale[lane + 64], bias[lane + 64]);
  cb[c * DIM + lane] = o0;
  cb[c * DIM + lane + 64] = o1;
  const float ss = wave_sum(fmaf(o0, o0, o1 * o1));
  if (lane == 0) cnorm2[c] = ss;

  if (cbcat != nullptr) {
    const int ct = c >> 7, r = c & 127;
    const unsigned int swz = ((r >> 1) & 3) << 3;
    unsigned short* base = cbcat + (size_t)ct * (KT * TILE);
#pragma unroll
    for (int h = 0; h < 2; ++h) {
      const int d = lane + 64 * h;
      const float val = h ? o1 : o0;
      const unsigned short hi = f2bf(val);
      const unsigned short lo = f2bf(val - bf2f(hi));
      const int ktl = d >> 5;                    // 0..3 within segment
      const int off = (r << 5) + ((d & 31) ^ swz);
      base[ktl * TILE + off] = hi;               // seg0: hi (pairs Z hi)
      base[(4 + ktl) * TILE + off] = lo;         // seg1: lo (pairs Z hi)
      base[(8 + ktl) * TILE + off] = hi;         // seg2: hi (pairs Z lo)
    }
  }
}

// --- K0c: Zcat tiles (hi, hi, lo), swizzled ------------------------------
__global__ __launch_bounds__(256) void zprep_kernel(
    const float* __restrict__ z, unsigned short* __restrict__ zcat) {
  const int id = blockIdx.x * 256 + threadIdx.x;  // 16384*48 exact
  const int row = id / 48, s = id - row * 48;
  const int kt = s >> 2, s4 = s & 3;
  const int seg = kt >> 2;                       // 0,1: hi   2: lo
  const int d0 = ((kt & 3) << 5) + (s4 << 3);
  const int r = row & 127, rb = row >> 7;
  const int slotsw = s4 ^ ((r >> 1) & 3);

  const float* zp = &z[(size_t)row * DIM + d0];
  u16x8 out;
#pragma unroll
  for (int i = 0; i < 8; ++i) {
    const float x = zp[i];
    unsigned short b = f2bf(x);
    if (seg == 2) b = f2bf(x - bf2f(b));
    out[i] = b;
  }
  *(u16x8*)&zcat[(size_t)(rb * KT + kt) * TILE + (r << 5) + (slotsw << 3)] =
      out;
}

// --- K1: MFMA distance GEMM + per-tile argmin ----------------------------
// grid 8192 = 128 row-tiles x 64 code-tiles; 256 thr = 4 waves (2x2 of 64x64)
__global__ __launch_bounds__(256, 2) void mfma_argmin_kernel(
    const unsigned short* __restrict__ zcat,
    const unsigned short* __restrict__ cbcat,
    const float* __restrict__ cnorm2, float* __restrict__ pval,
    int* __restrict__ pidx) {
  __shared__ __align__(16) unsigned short As[TILE];
  __shared__ __align__(16) unsigned short Bs[TILE];
  __shared__ float exv[2][128];
  __shared__ int exi[2][128];

  const int bid = blockIdx.x;
  const int swz = ((bid & 7) << 10) + (bid >> 3);  // XCD-bijective (8192%8==0)
  const int rb = swz >> 6;  // 0..127 row tile
  const int ct = swz & 63;  // 0..63  code tile

  const int tid = threadIdx.x;
  const int lane = tid & 63, wid = tid >> 6;
  const int wr = wid >> 1, wc = wid & 1;
  const int l15 = lane & 15, lg = lane >> 4;

  const unsigned short* Ag = zcat + (size_t)rb * (KT * TILE);
  const unsigned short* Bg = cbcat + (size_t)ct * (KT * TILE);
  const int soff = (wid << 9) + (lane << 3);  // staging elem offset, issue 0

  f32x4 acc[4][4];
#pragma unroll
  for (int mi = 0; mi < 4; ++mi)
#pragma unroll
    for (int ni = 0; ni < 4; ++ni) acc[mi][ni] = f32x4{0.f, 0.f, 0.f, 0.f};

  int aoff[4], boff[4];
#pragma unroll
  for (int i = 0; i < 4; ++i) {
    const int ra = wr * 64 + i * 16 + l15;
    aoff[i] = (ra << 5) + ((lg << 3) ^ (((ra >> 1) & 3) << 3));
    const int rc = wc * 64 + i * 16 + l15;
    boff[i] = (rc << 5) + ((lg << 3) ^ (((rc >> 1) & 3) << 3));
  }

  for (int kt = 0; kt < KT; ++kt) {
    __syncthreads();  // previous tile's ds_reads complete
    const unsigned short* ag = Ag + kt * TILE;
    const unsigned short* bg = Bg + kt * TILE;
#pragma unroll
    for (int i = 0; i < 2; ++i) {
      gload_lds16(ag + soff + (i << 11), As + (wid << 9) + (i << 11));
      gload_lds16(bg + soff + (i << 11), Bs + (wid << 9) + (i << 11));
    }
    __syncthreads();  // compiler drains vmcnt(0) here

    bf16x8 af[4], bf[4];
#pragma unroll
    for (int i = 0; i < 4; ++i) af[i] = *(const bf16x8*)&As[aoff[i]];
#pragma unroll
    for (int i = 0; i < 4; ++i) bf[i] = *(const bf16x8*)&Bs[boff[i]];
#pragma unroll
    for (int mi = 0; mi < 4; ++mi)
#pragma unroll
      for (int ni = 0; ni < 4; ++ni)
        acc[mi][ni] = __builtin_amdgcn_mfma_f32_16x16x32_bf16(
            af[mi], bf[ni], acc[mi][ni], 0, 0, 0);
  }

  // ---- epilogue: dist = cn - 2*dot ; argmin over this block's 128 codes
  float cn[4];
#pragma unroll
  for (int ni = 0; ni < 4; ++ni)
    cn[ni] = cnorm2[ct * 128 + wc * 64 + ni * 16 + l15];

#pragma unroll
  for (int mi = 0; mi < 4; ++mi) {
#pragma unroll
    for (int rg = 0; rg < 4; ++rg) {
      float bv = 3.4e38f;
      int bi = 0;
#pragma unroll
      for (int ni = 0; ni < 4; ++ni) {
        const float d = fmaf(-2.f, acc[mi][ni][rg], cn[ni]);
        if (d < bv) { bv = d; bi = ct * 128 + wc * 64 + ni * 16 + l15; }
      }
#pragma unroll
      for (int off = 1; off < 16; off <<= 1) {
        const float ov = __shfl_xor(bv, off, 64);
        const int oi = __shfl_xor(bi, off, 64);
        if (ov < bv || (ov == bv && oi < bi)) { bv = ov; bi = oi; }
      }
      if (l15 == 0) {
        const int rloc = wr * 64 + mi * 16 + (lg << 2) + rg;
        exv[wc][rloc] = bv;
        exi[wc][rloc] = bi;
      }
    }
  }
  __syncthreads();
  if (tid < 128) {
    const float v0 = exv[0][tid], v1 = exv[1][tid];
    const int i0 = exi[0][tid], i1 = exi[1][tid];
    const int row = rb * 128 + tid;
    const bool t = (v1 < v0);  // tie -> wc=0 (lower code)
    pval[(size_t)ct * NROWS + row] = t ? v1 : v0;
    pidx[(size_t)ct * NROWS + row] = t ? i1 : i0;
  }
}

// --- K1b: reduce 64 code-tile partials per row ---------------------------
__global__ __launch_bounds__(256) void argmin_reduce_kernel(
    const float* __restrict__ pval, const int* __restrict__ pidx,
    int* __restrict__ fidx) {
  const int row = blockIdx.x * 256 + threadIdx.x;
  float bv = pval[row];
  int bi = pidx[row];
  for (int t = 1; t < 64; ++t) {
    const float v = pval[(size_t)t * NROWS + row];
    if (v < bv) { bv = v; bi = pidx[(size_t)t * NROWS + row]; }  // tie: earlier tile
  }
  fidx[row] = bi;
}

// ===================== fallback fp32 argmin (round-1) ====================
__global__ __launch_bounds__(256, 1) void argmin_kernel(
    const float* __restrict__ z, const float* __restrict__ cb,
    const float* __restrict__ cnorm2, float* __restrict__ cand_val,
    int* __restrict__ cand_idx) {
  __shared__ float zs[128][DIM];
  __shared__ float cs[128][DIM];

  const int tid = threadIdx.x;
  const int rb = blockIdx.x >> 1;
  const int ch = blockIdx.x & 1;
  const int row0 = rb * 128;
  const int code0 = ch * (NCODE / 2);

  for (int i = tid; i < 128 * 32; i += 256) {
    const int r = i >> 5, f = i & 31;
    *(float4*)&zs[r][f << 2] = *(const float4*)&z[(row0 + r) * DIM + (f << 2)];
  }

  const int tx = tid & 15, ty = tid >> 4;
  const int sw = tx & 7;

  float best[8];
  int besti[8];
#pragma unroll
  for (int r = 0; r < 8; ++r) { best[r] = 3.4e38f; besti[r] = 0; }

  for (int cc = 0; cc < NCODE / 2; cc += 128) {
    __syncthreads();
    for (int i = tid; i < 128 * 32; i += 256) {
      const int r = i >> 5, f = i & 31;
      const int fg = f ^ (r & 7);
      *(float4*)&cs[r][f << 2] =
          *(const float4*)&cb[(code0 + cc + r) * DIM + (fg << 2)];
    }
    __syncthreads();

    float acc[8][8];
#pragma unroll
    for (int r = 0; r < 8; ++r)
#pragma unroll
      for (int j = 0; j < 8; ++j) acc[r][j] = 0.f;

    for (int k = 0; k < DIM; k += 4) {
      const int f = k >> 2;
      float4 zr[8], cr[8];
#pragma unroll
      for (int r = 0; r < 8; ++r) zr[r] = *(const float4*)&zs[ty + 16 * r][k];
      const int col = ((f ^ sw) << 2);
#pragma unroll
      for (int j = 0; j < 8; ++j) cr[j] = *(const float4*)&cs[tx + 16 * j][col];
#pragma unroll
      for (int r = 0; r < 8; ++r)
#pragma unroll
        for (int j = 0; j < 8; ++j) {
          acc[r][j] = fmaf(zr[r].x, cr[j].x, acc[r][j]);
          acc[r][j] = fmaf(zr[r].y, cr[j].y, acc[r][j]);
          acc[r][j] = fmaf(zr[r].z, cr[j].z, acc[r][j]);
          acc[r][j] = fmaf(zr[r].w, cr[j].w, acc[r][j]);
        }
    }

#pragma unroll
    for (int j = 0; j < 8; ++j) {
      const int code = code0 + cc + tx + 16 * j;
      const float cnv = cnorm2[code];
#pragma unroll
      for (int r = 0; r < 8; ++r) {
        const float s = fmaf(-2.f, acc[r][j], cnv);
        if (s < best[r]) { best[r] = s; besti[r] = code; }
      }
    }
  }

#pragma unroll
  for (int off = 1; off < 16; off <<= 1) {
#pragma unroll
    for (int r = 0; r < 8; ++r) {
      const float ov = __shfl_xor(best[r], off, 64);
      const int oi = __shfl_xor(besti[r], off, 64);
      if (ov < best[r] || (ov == best[r] && oi < besti[r])) {
        best[r] = ov;
        besti[r] = oi;
      }
    }
  }
  if (tx == 0) {
#pragma unroll
    for (int r = 0; r < 8; ++r) {
      const int row = row0 + ty + 16 * r;
      cand_val[row * 2 + ch] = best[r];
      cand_idx[row * 2 + ch] = besti[r];
    }
  }
}

__global__ __launch_bounds__(256) void merge_kernel(
    const float* __restrict__ cand_val, const int* __restrict__ cand_idx,
    int* __restrict__ fidx) {
  const int row = blockIdx.x * 256 + threadIdx.x;
  const float v0 = cand_val[row * 2], v1 = cand_val[row * 2 + 1];
  fidx[row] = (v1 < v0) ? cand_idx[row * 2 + 1] : cand_idx[row * 2];
}

// --- K2: gather, rotation trick, commit partials -------------------------
__global__ __launch_bounds__(256) void rotate_kernel(
    const float* __restrict__ z, const float* __restrict__ cb,
    const int* __restrict__ fidx, float* __restrict__ out_zq,
    float* __restrict__ out_idx, float* __restrict__ partials) {
  const int tid = threadIdx.x;
  const int wid = tid >> 6, lane = tid & 63;
  const int row = blockIdx.x * 4 + wid;
  const int ci = fidx[row];

  const float z0 = z[row * DIM + lane], z1 = z[row * DIM + lane + 64];
  const float c0 = cb[ci * DIM + lane], c1 = cb[ci * DIM + lane + 64];

  const float ns2 = wave_sum(fmaf(z0, z0, z1 * z1));
  const float nt2 = wave_sum(fmaf(c0, c0, c1 * c1));
  const float ns = sqrtf(ns2), nt = sqrtf(nt2);
  const float dns = fmaxf(ns, EPSF), dnt = fmaxf(nt, EPSF);
  const float u0 = z0 / dns, u1 = z1 / dns;
  const float q0 = c0 / dnt, q1 = c1 / dnt;
  float w0 = u0 + q0, w1 = u1 + q1;
  const float nw = sqrtf(wave_sum(fmaf(w0, w0, w1 * w1)));
  const float dnw = fmaxf(nw, EPSF);
  w0 /= dnw;
  w1 /= dnw;
  const float ew = wave_sum(fmaf(z0, w0, z1 * w1));
  const float eu = wave_sum(fmaf(z0, u0, z1 * u1));
  const float sc = nt / dns;
  const float o0 = (z0 - 2.f * ew * w0 + 2.f * eu * q0) * sc;
  const float o1 = (z1 - 2.f * ew * w1 + 2.f * eu * q1) * sc;
  out_zq[row * DIM + lane] = o0;
  out_zq[row * DIM + lane + 64] = o1;
  if (lane == 0) out_idx[row] = (float)ci;

  const float d0 = z0 - c0, d1 = z1 - c1;
  const float rsum = wave_sum(fmaf(d0, d0, d1 * d1));
  __shared__ float pr[4];
  if (lane == 0) pr[wid] = rsum;
  __syncthreads();
  if (tid == 0) partials[blockIdx.x] = (pr[0] + pr[1]) + (pr[2] + pr[3]);
}

// --- K3: deterministic final reduction for commit ------------------------
__global__ void finalize_kernel(const float* __restrict__ partials,
                                float* __restrict__ out_commit) {
  __shared__ float red[256];
  const int tid = threadIdx.x;
  float s = 0.f;
  for (int i = tid; i < 4096; i += 256) s += partials[i];
  red[tid] = s;
  __syncthreads();
  for (int off = 128; off > 0; off >>= 1) {
    if (tid < off) red[tid] += red[tid + off];
    __syncthreads();
  }
  if (tid == 0) out_commit[0] = red[0] * (1.25f / ((float)NROWS * (float)DIM));
}

extern "C" void kernel_launch(void* const* d_in, const int* in_sizes, int n_in,
                              void* d_out, int out_size, void* d_ws,
                              size_t ws_size, hipStream_t stream) {
  const float* z = (const float*)d_in[0];
  const float* fc = (const float*)d_in[1];
  const float* conv_v = (const float*)d_in[2];
  const float* conv_g = (const float*)d_in[3];
  const float* conv_b = (const float*)d_in[4];
  float* out = (float*)d_out;  // [zq 2097152][idx 16384][commit 1]

  float* ws = (float*)d_ws;
  float* cb = ws;
  float* cnorm2 = ws + 1048576;
  float* scale = ws + 1056768;

  if (ws_size >= WS_NEED_BYTES) {
    unsigned short* zcat = (unsigned short*)(ws + 1056896);
    unsigned short* cbcat = (unsigned short*)(ws + 4202624);
    float* pval = ws + 5775488;
    int* pidx = (int*)(ws + 6824064);
    int* fidx = (int*)(ws + 7872640);
    float* partials = ws + 7889024;

    scale_kernel<<<1, 128, 0, stream>>>(conv_v, conv_g, scale);
    codebook_kernel<<<NCODE / 4, 256, 0, stream>>>(fc, conv_v, scale, conv_b,
                                                   cb, cnorm2, cbcat);
    zprep_kernel<<<NROWS * 48 / 256, 256, 0, stream>>>(z, zcat);
    mfma_argmin_kernel<<<8192, 256, 0, stream>>>(zcat, cbcat, cnorm2, pval,
                                                 pidx);
    argmin_reduce_kernel<<<NROWS / 256, 256, 0, stream>>>(pval, pidx, fidx);
    rotate_kernel<<<NROWS / 4, 256, 0, stream>>>(z, cb, fidx, out,
                                                 out + 2097152, partials);
    finalize_kernel<<<1, 256, 0, stream>>>(partials, out + 2113536);
  } else {
    float* cand_val = ws + 1056896;
    int* cand_idx = (int*)(ws + 1089664);
    int* fidx = (int*)(ws + 1122432);
    float* partials = ws + 1138816;

    scale_kernel<<<1, 128, 0, stream>>>(conv_v, conv_g, scale);
    codebook_kernel<<<NCODE / 4, 256, 0, stream>>>(fc, conv_v, scale, conv_b,
                                                   cb, cnorm2, nullptr);
    argmin_kernel<<<256, 256, 0, stream>>>(z, cb, cnorm2, cand_val, cand_idx);
    merge_kernel<<<NROWS / 256, 256, 0, stream>>>(cand_val, cand_idx, fidx);
    rotate_kernel<<<NROWS / 4, 256, 0, stream>>>(z, cb, fidx, out,
                                                 out + 2097152, partials);
    finalize_kernel<<<1, 256, 0, stream>>>(partials, out + 2113536);
  }
}

// Round 3
// 221.484 us; speedup vs baseline: 2.9880x; 1.3130x over previous
//
#include <hip/hip_runtime.h>
#include <math.h>

#define NROWS 16384  // B*T
#define DIM 128
#define NCODE 8192
#define EPSF 1e-12f

typedef float f32x4 __attribute__((ext_vector_type(4)));
typedef __bf16 bf16x8 __attribute__((ext_vector_type(8)));
typedef unsigned short u16x8 __attribute__((ext_vector_type(8)));

// ---------------- MFMA-path ws layout (float offsets) ----------------
// cb       : 0          (1048576)
// cnorm2   : 1048576    (8192)
// Wt       : 1056768    (16384)   [k][d] f32, scale folded in
// Zcat     : 1073152    (3145728 f32 slots = 16384*384 u16)
// CBcat    : 4218880    (1572864 f32 slots =  8192*384 u16)
// pval     : 5791744    (1048576)  [64 tiles][16384 rows]
// pidx     : 6840320    (1048576)
// partials : 7888896    (4096)
// end        7892992 floats = 31,571,968 bytes
#define WS_NEED_BYTES 31571968ull

// K = 384 = 12 k-tiles of 32.  Z segs: [hi|hi|lo]; CB segs: [hi|lo|hi].
// Tile layout (both Zcat and CBcat): [blk][kt 0..11][128 rows][32 k] bf16,
// with slot swizzle: elem(r,k) stored at (r<<5) + (k ^ (((r>>1)&3)<<3)).
#define KT 12
#define TILE 4096  // 128*32 elems

__device__ __forceinline__ float wave_sum(float x) {
#pragma unroll
  for (int off = 32; off > 0; off >>= 1) x += __shfl_xor(x, off, 64);
  return x;
}

__device__ __forceinline__ unsigned short f2bf(float x) {
  union { float f; unsigned int u; } v;
  v.f = x;
  unsigned int r = v.u + 0x7fffu + ((v.u >> 16) & 1u);
  return (unsigned short)(r >> 16);
}
__device__ __forceinline__ float bf2f(unsigned short h) {
  union { float f; unsigned int u; } v;
  v.u = ((unsigned int)h) << 16;
  return v.f;
}

__device__ __forceinline__ void gload_lds16(const unsigned short* g,
                                            unsigned short* l) {
  __builtin_amdgcn_global_load_lds(
      (const __attribute__((address_space(1))) void*)g,
      (__attribute__((address_space(3))) void*)l, 16, 0, 0);
}

// --- K0a: Wt[k][d] = v[d][k] * g[d]/||v[d]|| -----------------------------
__global__ void wprep_kernel(const float* __restrict__ v,
                             const float* __restrict__ g,
                             float* __restrict__ Wt) {
  const int d = blockIdx.x;       // 128 blocks
  const int lane = threadIdx.x;   // 64 threads = 1 wave
  const float v0 = v[d * DIM + lane], v1 = v[d * DIM + lane + 64];
  const float ss = wave_sum(fmaf(v0, v0, v1 * v1));
  const float sc = g[d] / sqrtf(ss);
  Wt[lane * DIM + d] = v0 * sc;
  Wt[(lane + 64) * DIM + d] = v1 * sc;
}

// --- K0b: cb[c][d] = fc[c]·Wt[:,d] + b[d]; cnorm2; cbcat hi/lo tiles -----
// grid 512, block 256 (4 waves); 16 codes per block, 4 per wave.
__global__ __launch_bounds__(256, 2) void codebook_kernel(
    const float* __restrict__ fc, const float* __restrict__ Wt,
    const float* __restrict__ bias, float* __restrict__ cb,
    float* __restrict__ cnorm2, unsigned short* __restrict__ cbcat) {
  __shared__ float Ws[DIM][DIM];  // 64 KiB, [k][d]
  const int tid = threadIdx.x;
  for (int i = tid; i < 4096; i += 256)
    *(float4*)&Ws[0][i << 2] = *(const float4*)&Wt[i << 2];
  __syncthreads();

  const int lane = tid & 63, wid = tid >> 6;
  const int c0 = blockIdx.x * 16 + wid * 4;
  const float b0 = bias[lane], b1 = bias[lane + 64];

  for (int cc = 0; cc < 4; ++cc) {
    const int c = __builtin_amdgcn_readfirstlane(c0 + cc);
    float a0 = 0.f, a1 = 0.f;
    for (int k = 0; k < DIM; k += 4) {
      const float4 f4 = *(const float4*)&fc[c * DIM + k];
      a0 = fmaf(f4.x, Ws[k][lane], a0);
      a1 = fmaf(f4.x, Ws[k][lane + 64], a1);
      a0 = fmaf(f4.y, Ws[k + 1][lane], a0);
      a1 = fmaf(f4.y, Ws[k + 1][lane + 64], a1);
      a0 = fmaf(f4.z, Ws[k + 2][lane], a0);
      a1 = fmaf(f4.z, Ws[k + 2][lane + 64], a1);
      a0 = fmaf(f4.w, Ws[k + 3][lane], a0);
      a1 = fmaf(f4.w, Ws[k + 3][lane + 64], a1);
    }
    const float o0 = a0 + b0, o1 = a1 + b1;
    cb[c * DIM + lane] = o0;
    cb[c * DIM + lane + 64] = o1;
    const float ss = wave_sum(fmaf(o0, o0, o1 * o1));
    if (lane == 0) cnorm2[c] = ss;

    if (cbcat != nullptr) {
      const int ct = c >> 7, r = c & 127;
      const unsigned int swz = ((r >> 1) & 3) << 3;
      unsigned short* base = cbcat + (size_t)ct * (KT * TILE);
#pragma unroll
      for (int h = 0; h < 2; ++h) {
        const int d = lane + 64 * h;
        const float val = h ? o1 : o0;
        const unsigned short hi = f2bf(val);
        const unsigned short lo = f2bf(val - bf2f(hi));
        const int ktl = d >> 5;
        const int off = (r << 5) + ((d & 31) ^ swz);
        base[ktl * TILE + off] = hi;        // seg0: hi (pairs Z hi)
        base[(4 + ktl) * TILE + off] = lo;  // seg1: lo (pairs Z hi)
        base[(8 + ktl) * TILE + off] = hi;  // seg2: hi (pairs Z lo)
      }
    }
  }
}

// --- K0c: Zcat tiles (hi, hi, lo), swizzled ------------------------------
__global__ __launch_bounds__(256) void zprep_kernel(
    const float* __restrict__ z, unsigned short* __restrict__ zcat) {
  const int id = blockIdx.x * 256 + threadIdx.x;  // 16384*48 exact
  const int row = id / 48, s = id - row * 48;
  const int kt = s >> 2, s4 = s & 3;
  const int seg = kt >> 2;  // 0,1: hi   2: lo
  const int d0 = ((kt & 3) << 5) + (s4 << 3);
  const int r = row & 127, rb = row >> 7;
  const int slotsw = s4 ^ ((r >> 1) & 3);

  const float* zp = &z[(size_t)row * DIM + d0];
  u16x8 out;
#pragma unroll
  for (int i = 0; i < 8; ++i) {
    const float x = zp[i];
    unsigned short b = f2bf(x);
    if (seg == 2) b = f2bf(x - bf2f(b));
    out[i] = b;
  }
  *(u16x8*)&zcat[(size_t)(rb * KT + kt) * TILE + (r << 5) + (slotsw << 3)] =
      out;
}

// --- K1: MFMA distance GEMM + per-tile argmin, 2-phase double-buffer -----
// grid 8192 = 128 row-tiles x 64 code-tiles; 256 thr = 4 waves (2x2 of 64x64)
__global__ __launch_bounds__(256, 4) void mfma_argmin_kernel(
    const unsigned short* __restrict__ zcat,
    const unsigned short* __restrict__ cbcat,
    const float* __restrict__ cnorm2, float* __restrict__ pval,
    int* __restrict__ pidx) {
  __shared__ __align__(16) unsigned short As[2][TILE];  // 16 KiB
  __shared__ __align__(16) unsigned short Bs[2][TILE];  // 16 KiB

  const int bid = blockIdx.x;
  const int swz = ((bid & 7) << 10) + (bid >> 3);  // XCD-bijective (8192%8==0)
  const int rb = swz >> 6;
  const int ct = swz & 63;

  const int tid = threadIdx.x;
  const int lane = tid & 63, wid = tid >> 6;
  const int wr = wid >> 1, wc = wid & 1;
  const int l15 = lane & 15, lg = lane >> 4;

  const unsigned short* Ag = zcat + (size_t)rb * (KT * TILE);
  const unsigned short* Bg = cbcat + (size_t)ct * (KT * TILE);
  const int soff = (wid << 9) + (lane << 3);
  const int ldst = (wid << 9);

  f32x4 acc[4][4];
#pragma unroll
  for (int mi = 0; mi < 4; ++mi)
#pragma unroll
    for (int ni = 0; ni < 4; ++ni) acc[mi][ni] = f32x4{0.f, 0.f, 0.f, 0.f};

  int aoff[4], boff[4];
#pragma unroll
  for (int i = 0; i < 4; ++i) {
    const int ra = wr * 64 + i * 16 + l15;
    aoff[i] = (ra << 5) + ((lg << 3) ^ (((ra >> 1) & 3) << 3));
    const int rc = wc * 64 + i * 16 + l15;
    boff[i] = (rc << 5) + ((lg << 3) ^ (((rc >> 1) & 3) << 3));
  }

  // prologue: stage kt=0 into buffer 0
#pragma unroll
  for (int i = 0; i < 2; ++i) {
    gload_lds16(Ag + soff + (i << 11), &As[0][ldst + (i << 11) + (lane << 3)]);
    gload_lds16(Bg + soff + (i << 11), &Bs[0][ldst + (i << 11) + (lane << 3)]);
  }
  __syncthreads();  // drains vmcnt(0): tile 0 resident

  for (int kt = 0; kt < KT; ++kt) {
    const int cur = kt & 1;
    if (kt + 1 < KT) {  // stage next tile into the other buffer (race-free:
      // all reads of buf cur^1 finished before the barrier we just crossed)
      const unsigned short* ag = Ag + (kt + 1) * TILE;
      const unsigned short* bg = Bg + (kt + 1) * TILE;
#pragma unroll
      for (int i = 0; i < 2; ++i) {
        gload_lds16(ag + soff + (i << 11),
                    &As[cur ^ 1][ldst + (i << 11) + (lane << 3)]);
        gload_lds16(bg + soff + (i << 11),
                    &Bs[cur ^ 1][ldst + (i << 11) + (lane << 3)]);
      }
    }
    bf16x8 af[4], bfr[4];
#pragma unroll
    for (int i = 0; i < 4; ++i) af[i] = *(const bf16x8*)&As[cur][aoff[i]];
#pragma unroll
    for (int i = 0; i < 4; ++i) bfr[i] = *(const bf16x8*)&Bs[cur][boff[i]];
#pragma unroll
    for (int mi = 0; mi < 4; ++mi)
#pragma unroll
      for (int ni = 0; ni < 4; ++ni)
        acc[mi][ni] = __builtin_amdgcn_mfma_f32_16x16x32_bf16(
            af[mi], bfr[ni], acc[mi][ni], 0, 0, 0);
    __syncthreads();  // drains my stage loads + all waves' ds_reads
  }

  // ---- epilogue: dist = cn - 2*dot ; argmin over this block's 128 codes
  // overlay exchange buffers on As/Bs (all LDS reads retired at last barrier)
  float* exv = (float*)&As[0][0];  // [2][128] floats
  int* exi = (int*)&Bs[0][0];      // [2][128] ints

  float cn[4];
#pragma unroll
  for (int ni = 0; ni < 4; ++ni)
    cn[ni] = cnorm2[ct * 128 + wc * 64 + ni * 16 + l15];

#pragma unroll
  for (int mi = 0; mi < 4; ++mi) {
#pragma unroll
    for (int rg = 0; rg < 4; ++rg) {
      float bv = 3.4e38f;
      int bi = 0;
#pragma unroll
      for (int ni = 0; ni < 4; ++ni) {
        const float d = fmaf(-2.f, acc[mi][ni][rg], cn[ni]);
        if (d < bv) { bv = d; bi = ct * 128 + wc * 64 + ni * 16 + l15; }
      }
#pragma unroll
      for (int off = 1; off < 16; off <<= 1) {
        const float ov = __shfl_xor(bv, off, 64);
        const int oi = __shfl_xor(bi, off, 64);
        if (ov < bv || (ov == bv && oi < bi)) { bv = ov; bi = oi; }
      }
      if (l15 == 0) {
        const int rloc = wr * 64 + mi * 16 + (lg << 2) + rg;
        exv[wc * 128 + rloc] = bv;
        exi[wc * 128 + rloc] = bi;
      }
    }
  }
  __syncthreads();
  if (tid < 128) {
    const float v0 = exv[tid], v1 = exv[128 + tid];
    const int i0 = exi[tid], i1 = exi[128 + tid];
    const int row = rb * 128 + tid;
    const bool t = (v1 < v0);  // tie -> wc=0 (lower code)
    pval[(size_t)ct * NROWS + row] = t ? v1 : v0;
    pidx[(size_t)ct * NROWS + row] = t ? i1 : i0;
  }
}

// ===================== fallback fp32 argmin (round-1) ====================
__global__ __launch_bounds__(256, 1) void argmin_kernel(
    const float* __restrict__ z, const float* __restrict__ cb,
    const float* __restrict__ cnorm2, float* __restrict__ pval,
    int* __restrict__ pidx) {
  __shared__ float zs[128][DIM];
  __shared__ float cs[128][DIM];

  const int tid = threadIdx.x;
  const int rb = blockIdx.x >> 1;
  const int ch = blockIdx.x & 1;
  const int row0 = rb * 128;
  const int code0 = ch * (NCODE / 2);

  for (int i = tid; i < 128 * 32; i += 256) {
    const int r = i >> 5, f = i & 31;
    *(float4*)&zs[r][f << 2] = *(const float4*)&z[(row0 + r) * DIM + (f << 2)];
  }

  const int tx = tid & 15, ty = tid >> 4;
  const int sw = tx & 7;

  float best[8];
  int besti[8];
#pragma unroll
  for (int r = 0; r < 8; ++r) { best[r] = 3.4e38f; besti[r] = 0; }

  for (int cc = 0; cc < NCODE / 2; cc += 128) {
    __syncthreads();
    for (int i = tid; i < 128 * 32; i += 256) {
      const int r = i >> 5, f = i & 31;
      const int fg = f ^ (r & 7);
      *(float4*)&cs[r][f << 2] =
          *(const float4*)&cb[(code0 + cc + r) * DIM + (fg << 2)];
    }
    __syncthreads();

    float acc[8][8];
#pragma unroll
    for (int r = 0; r < 8; ++r)
#pragma unroll
      for (int j = 0; j < 8; ++j) acc[r][j] = 0.f;

    for (int k = 0; k < DIM; k += 4) {
      const int f = k >> 2;
      float4 zr[8], cr[8];
#pragma unroll
      for (int r = 0; r < 8; ++r) zr[r] = *(const float4*)&zs[ty + 16 * r][k];
      const int col = ((f ^ sw) << 2);
#pragma unroll
      for (int j = 0; j < 8; ++j) cr[j] = *(const float4*)&cs[tx + 16 * j][col];
#pragma unroll
      for (int r = 0; r < 8; ++r)
#pragma unroll
        for (int j = 0; j < 8; ++j) {
          acc[r][j] = fmaf(zr[r].x, cr[j].x, acc[r][j]);
          acc[r][j] = fmaf(zr[r].y, cr[j].y, acc[r][j]);
          acc[r][j] = fmaf(zr[r].z, cr[j].z, acc[r][j]);
          acc[r][j] = fmaf(zr[r].w, cr[j].w, acc[r][j]);
        }
    }

#pragma unroll
    for (int j = 0; j < 8; ++j) {
      const int code = code0 + cc + tx + 16 * j;
      const float cnv = cnorm2[code];
#pragma unroll
      for (int r = 0; r < 8; ++r) {
        const float s = fmaf(-2.f, acc[r][j], cnv);
        if (s < best[r]) { best[r] = s; besti[r] = code; }
      }
    }
  }

#pragma unroll
  for (int off = 1; off < 16; off <<= 1) {
#pragma unroll
    for (int r = 0; r < 8; ++r) {
      const float ov = __shfl_xor(best[r], off, 64);
      const int oi = __shfl_xor(besti[r], off, 64);
      if (ov < best[r] || (ov == best[r] && oi < besti[r])) {
        best[r] = ov;
        besti[r] = oi;
      }
    }
  }
  if (tx == 0) {
#pragma unroll
    for (int r = 0; r < 8; ++r) {
      const int row = row0 + ty + 16 * r;
      pval[(size_t)ch * NROWS + row] = best[r];
      pidx[(size_t)ch * NROWS + row] = besti[r];
    }
  }
}

// --- K2: tile-argmin reduce + gather + rotation + commit partials --------
__global__ __launch_bounds__(256) void rotate_kernel(
    const float* __restrict__ z, const float* __restrict__ cb,
    const float* __restrict__ pval, const int* __restrict__ pidx, int ntiles,
    float* __restrict__ out_zq, float* __restrict__ out_idx,
    float* __restrict__ partials) {
  const int tid = threadIdx.x;
  const int wid = tid >> 6, lane = tid & 63;
  const int row = blockIdx.x * 4 + wid;

  // lane-parallel reduce over code-tile partials
  float bv = 3.4e38f;
  int bi = 0x7fffffff;
  if (lane < ntiles) {
    bv = pval[(size_t)lane * NROWS + row];
    bi = pidx[(size_t)lane * NROWS + row];
  }
#pragma unroll
  for (int off = 32; off > 0; off >>= 1) {
    const float ov = __shfl_xor(bv, off, 64);
    const int oi = __shfl_xor(bi, off, 64);
    if (ov < bv || (ov == bv && oi < bi)) { bv = ov; bi = oi; }
  }
  const int ci = bi;

  const float z0 = z[row * DIM + lane], z1 = z[row * DIM + lane + 64];
  const float c0 = cb[ci * DIM + lane], c1 = cb[ci * DIM + lane + 64];

  const float ns2 = wave_sum(fmaf(z0, z0, z1 * z1));
  const float nt2 = wave_sum(fmaf(c0, c0, c1 * c1));
  const float ns = sqrtf(ns2), nt = sqrtf(nt2);
  const float dns = fmaxf(ns, EPSF), dnt = fmaxf(nt, EPSF);
  const float u0 = z0 / dns, u1 = z1 / dns;
  const float q0 = c0 / dnt, q1 = c1 / dnt;
  float w0 = u0 + q0, w1 = u1 + q1;
  const float nw = sqrtf(wave_sum(fmaf(w0, w0, w1 * w1)));
  const float dnw = fmaxf(nw, EPSF);
  w0 /= dnw;
  w1 /= dnw;
  const float ew = wave_sum(fmaf(z0, w0, z1 * w1));
  const float eu = wave_sum(fmaf(z0, u0, z1 * u1));
  const float sc = nt / dns;
  const float o0 = (z0 - 2.f * ew * w0 + 2.f * eu * q0) * sc;
  const float o1 = (z1 - 2.f * ew * w1 + 2.f * eu * q1) * sc;
  out_zq[row * DIM + lane] = o0;
  out_zq[row * DIM + lane + 64] = o1;
  if (lane == 0) out_idx[row] = (float)ci;

  const float d0 = z0 - c0, d1 = z1 - c1;
  const float rsum = wave_sum(fmaf(d0, d0, d1 * d1));
  __shared__ float pr[4];
  if (lane == 0) pr[wid] = rsum;
  __syncthreads();
  if (tid == 0) partials[blockIdx.x] = (pr[0] + pr[1]) + (pr[2] + pr[3]);
}

// --- K3: deterministic final reduction for commit ------------------------
__global__ void finalize_kernel(const float* __restrict__ partials,
                                float* __restrict__ out_commit) {
  __shared__ float red[256];
  const int tid = threadIdx.x;
  float s = 0.f;
  for (int i = tid; i < 4096; i += 256) s += partials[i];
  red[tid] = s;
  __syncthreads();
  for (int off = 128; off > 0; off >>= 1) {
    if (tid < off) red[tid] += red[tid + off];
    __syncthreads();
  }
  if (tid == 0) out_commit[0] = red[0] * (1.25f / ((float)NROWS * (float)DIM));
}

extern "C" void kernel_launch(void* const* d_in, const int* in_sizes, int n_in,
                              void* d_out, int out_size, void* d_ws,
                              size_t ws_size, hipStream_t stream) {
  const float* z = (const float*)d_in[0];
  const float* fc = (const float*)d_in[1];
  const float* conv_v = (const float*)d_in[2];
  const float* conv_g = (const float*)d_in[3];
  const float* conv_b = (const float*)d_in[4];
  float* out = (float*)d_out;  // [zq 2097152][idx 16384][commit 1]

  float* ws = (float*)d_ws;
  float* cb = ws;
  float* cnorm2 = ws + 1048576;
  float* Wt = ws + 1056768;

  if (ws_size >= WS_NEED_BYTES) {
    unsigned short* zcat = (unsigned short*)(ws + 1073152);
    unsigned short* cbcat = (unsigned short*)(ws + 4218880);
    float* pval = ws + 5791744;
    int* pidx = (int*)(ws + 6840320);
    float* partials = ws + 7888896;

    wprep_kernel<<<DIM, 64, 0, stream>>>(conv_v, conv_g, Wt);
    codebook_kernel<<<NCODE / 16, 256, 0, stream>>>(fc, Wt, conv_b, cb, cnorm2,
                                                    cbcat);
    zprep_kernel<<<NROWS * 48 / 256, 256, 0, stream>>>(z, zcat);
    mfma_argmin_kernel<<<8192, 256, 0, stream>>>(zcat, cbcat, cnorm2, pval,
                                                 pidx);
    rotate_kernel<<<NROWS / 4, 256, 0, stream>>>(z, cb, pval, pidx, 64, out,
                                                 out + 2097152, partials);
    finalize_kernel<<<1, 256, 0, stream>>>(partials, out + 2113536);
  } else {
    float* pval = ws + 1073152;
    int* pidx = (int*)(ws + 1105920);
    float* partials = ws + 1138688;

    wprep_kernel<<<DIM, 64, 0, stream>>>(conv_v, conv_g, Wt);
    codebook_kernel<<<NCODE / 16, 256, 0, stream>>>(fc, Wt, conv_b, cb, cnorm2,
                                                    nullptr);
    argmin_kernel<<<256, 256, 0, stream>>>(z, cb, cnorm2, pval, pidx);
    rotate_kernel<<<NROWS / 4, 256, 0, stream>>>(z, cb, pval, pidx, 2, out,
                                                 out + 2097152, partials);
    finalize_kernel<<<1, 256, 0, stream>>>(partials, out + 2113536);
  }
}